// Round 11
// baseline (271.939 us; speedup 1.0000x reference)
//
#include <hip/hip_runtime.h>
#include <stdint.h>

typedef __bf16 bf16;
typedef __attribute__((ext_vector_type(8))) __bf16 bf16x8;
typedef __attribute__((ext_vector_type(4))) __bf16 bf16x4;
typedef __attribute__((ext_vector_type(4))) float f32x4;

#define DEVFN static __device__ __forceinline__

DEVFN void gload16(const bf16* g, char* l) {
  __builtin_amdgcn_global_load_lds(
      (const __attribute__((address_space(1))) void*)g,
      (__attribute__((address_space(3))) void*)l, 16, 0, 0);
}
DEVFN void gload4(const float* g, char* l) {
  __builtin_amdgcn_global_load_lds(
      (const __attribute__((address_space(1))) void*)g,
      (__attribute__((address_space(3))) void*)l, 4, 0, 0);
}

DEVFN int swz(int row, int kb) { return row * 128 + (kb ^ ((row & 7) << 4)); }

#define PS 9437184LL  // partial stride per kv-split: 16 bh * 4096 q * 144 B

// ---------------- prep: fp32 -> bf16 + weight transposes --------------------
__global__ __launch_bounds__(256) void prep_kernel(
    const float* __restrict__ x, const float* __restrict__ Wq,
    const float* __restrict__ Wk, const float* __restrict__ Wv,
    const float* __restrict__ Wp, bf16* __restrict__ xb,
    bf16* __restrict__ Wt, bf16* __restrict__ Wpt) {
  const int64_t tid = blockIdx.x * 256LL + threadIdx.x;
  const int64_t stride = (int64_t)gridDim.x * 256LL;
  for (int64_t i = tid; i < (8192LL * 512) / 4; i += stride) {
    float4 v = ((const float4*)x)[i];
    bf16x4 o = {(bf16)v.x, (bf16)v.y, (bf16)v.z, (bf16)v.w};
    ((bf16x4*)xb)[i] = o;
  }
  for (int64_t i = tid; i < 1536LL * 512; i += stride) {
    int c = (int)(i >> 9), k = (int)(i & 511);
    int wsel = c >> 9, cc = c & 511;
    const float* W = wsel == 0 ? Wq : (wsel == 1 ? Wk : Wv);
    Wt[i] = (bf16)W[k * 512 + cc];
  }
  for (int64_t i = tid; i < 512LL * 512; i += stride) {
    int c = (int)(i >> 9), k = (int)(i & 511);
    Wpt[i] = (bf16)Wp[k * 512 + c];
  }
}

// ---------------- shared 128x128 bf16 GEMM mainloop (K=512, BK=64) ----------
DEVFN void gemm_main(const bf16* __restrict__ A, const bf16* __restrict__ B,
                     int rowA0, int rowB0, char* sA, char* sB, f32x4 acc[4][4],
                     int wr, int wc, int lane, int w) {
#pragma unroll
  for (int m = 0; m < 4; m++)
#pragma unroll
    for (int n = 0; n < 4; n++) acc[m][n] = (f32x4){0.f, 0.f, 0.f, 0.f};
  const int lr = lane >> 3;
  const int kswz = 8 * ((lane & 7) ^ lr);
  for (int k0 = 0; k0 < 512; k0 += 64) {
#pragma unroll
    for (int j = 0; j < 4; j++) {
      const int c = w * 4 + j;
      gload16(A + (rowA0 + c * 8 + lr) * 512 + k0 + kswz, sA + c * 1024);
      gload16(B + (rowB0 + c * 8 + lr) * 512 + k0 + kswz, sB + c * 1024);
    }
    __syncthreads();
    bf16x8 af[4][2], bfv[4][2];
#pragma unroll
    for (int m = 0; m < 4; m++)
#pragma unroll
      for (int kk = 0; kk < 2; kk++) {
        af[m][kk] = *(const bf16x8*)(sA + swz(wr * 64 + m * 16 + (lane & 15),
                                              kk * 64 + (lane >> 4) * 16));
        bfv[m][kk] = *(const bf16x8*)(sB + swz(wc * 64 + m * 16 + (lane & 15),
                                               kk * 64 + (lane >> 4) * 16));
      }
#pragma unroll
    for (int m = 0; m < 4; m++)
#pragma unroll
      for (int n = 0; n < 4; n++)
#pragma unroll
        for (int kk = 0; kk < 2; kk++)
          acc[m][n] = __builtin_amdgcn_mfma_f32_16x16x32_bf16(
              af[m][kk], bfv[n][kk], acc[m][n], 0, 0, 0);
    __syncthreads();
  }
}

// ---------------- QKV projection ------------------------------------------
// Q is pre-scaled by 0.125*log2(e) so attention folds the softmax scale.
__global__ __launch_bounds__(256) void qkv_gemm(
    const bf16* __restrict__ xb, const bf16* __restrict__ Wt,
    const float* __restrict__ bq, const float* __restrict__ bk,
    const float* __restrict__ bv, bf16* __restrict__ Qb, bf16* __restrict__ Kb,
    bf16* __restrict__ Vt) {
  __shared__ __align__(128) char sA[16384];
  __shared__ __align__(128) char sB[16384];
  const int lane = threadIdx.x & 63, w = threadIdx.x >> 6;
  const int wr = w >> 1, wc = w & 1;
  const int rowA0 = blockIdx.y * 128;
  const int colB0 = blockIdx.x * 128;
  f32x4 acc[4][4];
  gemm_main(xb, Wt, rowA0, colB0, sA, sB, acc, wr, wc, lane, w);
  const int which = colB0 >> 9;
  const int cc0 = colB0 & 511;
  const float* bias = which == 0 ? bq : (which == 1 ? bk : bv);
  const float QSCALE = 0.18033688011112042f;  // 0.125 * log2(e)
#pragma unroll
  for (int m = 0; m < 4; m++)
#pragma unroll
    for (int n = 0; n < 4; n++)
#pragma unroll
      for (int r = 0; r < 4; r++) {
        int row = rowA0 + wr * 64 + m * 16 + (lane >> 4) * 4 + r;
        int col = cc0 + wc * 64 + n * 16 + (lane & 15);
        float v = acc[m][n][r] + bias[col];
        if (which == 0) {
          Qb[(int64_t)row * 512 + col] = (bf16)(v * QSCALE);
        } else if (which == 1) {
          Kb[(int64_t)row * 512 + col] = (bf16)v;
        } else {
          int b = row >> 12, nn = row & 4095;
          int hh = col >> 6, e = col & 63;
          Vt[(((int64_t)(b * 8 + hh)) * 64 + e) * 4096 + nn] = (bf16)v;
        }
      }
}

// ---------------- output projection (fp32 out) ----------------------------
__global__ __launch_bounds__(256) void out_gemm(const bf16* __restrict__ Ob,
                                                const bf16* __restrict__ Wpt,
                                                const float* __restrict__ bp,
                                                float* __restrict__ out) {
  __shared__ __align__(128) char sA[16384];
  __shared__ __align__(128) char sB[16384];
  const int lane = threadIdx.x & 63, w = threadIdx.x >> 6;
  const int wr = w >> 1, wc = w & 1;
  const int rowA0 = blockIdx.y * 128;
  const int colB0 = blockIdx.x * 128;
  f32x4 acc[4][4];
  gemm_main(Ob, Wpt, rowA0, colB0, sA, sB, acc, wr, wc, lane, w);
#pragma unroll
  for (int m = 0; m < 4; m++)
#pragma unroll
    for (int n = 0; n < 4; n++)
#pragma unroll
      for (int r = 0; r < 4; r++) {
        int row = rowA0 + wr * 64 + m * 16 + (lane >> 4) * 4 + r;
        int col = colB0 + wc * 64 + n * 16 + (lane & 15);
        out[(int64_t)row * 512 + col] = acc[m][n][r] + bp[col];
      }
}

// ---------------- fused flash attention: counted-vmcnt 3-buf pipeline ------
// Block = 1 head, 8 waves = 8 q-subwaves (16 q each, q-tile 128), half the
// kv range (2048 = 64 tiles of KVBLK=32). Grid 1024. 3-buffer ring staged
// via global_load_lds with UNIFORM 2 loads/wave/stage; raw s_barrier +
// s_waitcnt vmcnt(2) keeps tiles t+1,t+2 in flight across barriers (no
// vmcnt(0) drain -> staging latency hidden under 2 compute phases).
// Swapped QK^T; partials (m2, osum, o bf16) per q-row for combine.
__global__ __launch_bounds__(512) void attn_kernel(
    const bf16* __restrict__ Qb, const bf16* __restrict__ Kb,
    const bf16* __restrict__ Vt, const float* __restrict__ coords,
    const float* __restrict__ slopes, char* __restrict__ part) {
  __shared__ __align__(128) char sK[3 * 4096];  // [buf][32 kv][128B] swz
  __shared__ __align__(128) char sV[3 * 5120];  // [buf][64 e][80B]
  __shared__ __align__(128) char sC[3 * 256];   // [buf][32 kv float2]
  __shared__ __align__(128) char sP[8 * 1280];  // per-wave P [16q][80B]

  const int tid = threadIdx.x;
  const int lane = tid & 63, w = tid >> 6;
  const int c = lane & 15, g = lane >> 4;

  const int id = blockIdx.x;          // 0..1023
  const int bh = id & 15;             // bh%8 -> XCD
  const int qt = (id >> 4) & 31;
  const int ks = id >> 9;             // kv half
  const int b = bh >> 3, h = bh & 7;
  const int qw = qt * 128 + w * 16;
  const int bO = b * 4096;
  const int kvs = ks * 2048;

  const float LOG2E = 1.4426950408889634f;
  const float negsl2 = -slopes[h] * LOG2E;

  // Q fragments (B-operand of swapped QK^T): lane holds Q[q=c][hd=g*8+j]
  bf16x8 aq[2];
  {
    int64_t base = ((int64_t)(bO + qw + c)) * 512 + h * 64 + g * 8;
    aq[0] = *(const bf16x8*)(Qb + base);
    aq[1] = *(const bf16x8*)(Qb + base + 32);
  }
  const float* cbf = coords + (int64_t)bO * 2;
  float qcx, qcy;
  {
    float2 qc = ((const float2*)cbf)[qw + c];
    qcx = qc.x;
    qcy = qc.y;
  }

  bf16x8 ones;
#pragma unroll
  for (int jj = 0; jj < 8; jj++) ones[jj] = (bf16)1.0f;

  float m2 = -1e30f;
  f32x4 o[4], osum;
#pragma unroll
  for (int n = 0; n < 4; n++) o[n] = (f32x4){0.f, 0.f, 0.f, 0.f};
  osum = (f32x4){0.f, 0.f, 0.f, 0.f};

  const bf16* Kp = Kb + (int64_t)bO * 512 + h * 64;
  const bf16* Vp = Vt + (int64_t)(b * 8 + h) * 262144;

  // -------- staging: uniform 2 async loads per wave per tile --------
  // w0..3: K chunk w; w4..7: V chunk w-4. Second load: w1 -> coords
  // (gload4); all others -> duplicate V chunk 4 (identical data, benign).
  auto vaddr = [&](int j) {
    const int G = j * 64 + lane;
    const int row = (G * 52429) >> 18;  // G/5
    int gr = G - row * 5;
    if (gr > 3) gr = 0;  // pad lane: harmless dup
    return Vp + row * 4096 + kvs + gr * 8;
  };
  const bf16* kq = Kp + (int64_t)(kvs + w * 8 + (lane >> 3)) * 512 +
                   ((lane & 7) ^ ((lane >> 3) & 7)) * 8;
  const bf16* vq = vaddr(w & 3);           // role load (w>=4)
  const bf16* vx = vaddr(4);               // duplicate second load
  const float* cq = cbf + kvs * 2 + lane;  // w==1 second load

  auto STAGE = [&](char* kdst, char* vdst, char* cdst) {
    if (w < 4) {
      gload16(kq, kdst + w * 1024);
      kq += 32 * 512;
    } else {
      gload16(vq, vdst + (w & 3) * 1024);
      vq += 32;
    }
    if (w == 1) {
      gload4(cq, cdst);
      cq += 64;
    } else {
      gload16(vx, vdst + 4096);
      vx += 32;
    }
  };

  char *k0 = sK, *k1 = sK + 4096, *k2 = sK + 8192;
  char *v0 = sV, *v1 = sV + 5120, *v2 = sV + 10240;
  char *c0 = sC, *c1 = sC + 256, *c2 = sC + 512;

  STAGE(k0, v0, c0);  // tile 0
  STAGE(k1, v1, c1);  // tile 1

  char* pwv = sP + w * 1280;
  for (int tt = 0; tt < 64; ++tt) {
    // counted wait: force tile-tt loads done; keep tt+1 (and soon tt+2)
    // in flight. Tail uses vmcnt(0).
    if (tt < 63) {
      asm volatile("s_waitcnt vmcnt(2)" ::: "memory");
    } else {
      asm volatile("s_waitcnt vmcnt(0)" ::: "memory");
    }
    __builtin_amdgcn_sched_barrier(0);
    __builtin_amdgcn_s_barrier();
    __builtin_amdgcn_sched_barrier(0);
    if (tt + 2 < 64) STAGE(k2, v2, c2);

    // S^T = (K Q^T): lane holds q=c, kv = 16t+4g+r, t in {0,1}
    bf16x8 kf[2][2];
#pragma unroll
    for (int t = 0; t < 2; t++)
#pragma unroll
      for (int kk = 0; kk < 2; kk++)
        kf[t][kk] = *(const bf16x8*)(k0 + (t * 16 + c) * 128 +
                                     (((kk * 4 + g) ^ (c & 7)) * 16));
    float s[2][4];
    __builtin_amdgcn_s_setprio(1);
#pragma unroll
    for (int t = 0; t < 2; t++) {
      f32x4 sa = (f32x4){0.f, 0.f, 0.f, 0.f};
      sa = __builtin_amdgcn_mfma_f32_16x16x32_bf16(kf[t][0], aq[0], sa, 0, 0, 0);
      sa = __builtin_amdgcn_mfma_f32_16x16x32_bf16(kf[t][1], aq[1], sa, 0, 0, 0);
#pragma unroll
      for (int r = 0; r < 4; r++) s[t][r] = sa[r];
    }
    __builtin_amdgcn_s_setprio(0);

    // in-register bias from LDS-staged coords (broadcast reads)
#pragma unroll
    for (int t = 0; t < 2; t++) {
      f32x4 ca = *(const f32x4*)(c0 + 128 * t + 32 * g);
      f32x4 cb2 = *(const f32x4*)(c0 + 128 * t + 32 * g + 16);
      float dx, dy;
#define DIST1(T, R, CX, CY)                                              \
  dx = qcx - (CX);                                                       \
  dy = qcy - (CY);                                                       \
  s[T][R] = __builtin_fmaf(__builtin_amdgcn_sqrtf(dx * dx + dy * dy),    \
                           negsl2, s[T][R]);
      DIST1(t, 0, ca[0], ca[1])
      DIST1(t, 1, ca[2], ca[3])
      DIST1(t, 2, cb2[0], cb2[1])
      DIST1(t, 3, cb2[2], cb2[3])
#undef DIST1
    }

    // deferred online max (THR=8 base-2); row q=c lives on 4 g-lanes
    float lm = fmaxf(fmaxf(fmaxf(s[0][0], s[0][1]), fmaxf(s[0][2], s[0][3])),
                     fmaxf(fmaxf(s[1][0], s[1][1]), fmaxf(s[1][2], s[1][3])));
    lm = fmaxf(lm, __shfl_xor(lm, 16));
    lm = fmaxf(lm, __shfl_xor(lm, 32));
    if (__any(lm > m2 + 8.f)) {
      float nm = fmaxf(m2, lm);
      float sc = __builtin_amdgcn_exp2f(m2 - nm);
      m2 = nm;
      float scr[4];
#pragma unroll
      for (int r = 0; r < 4; r++)
        scr[r] = __shfl(sc, (lane & 48) | (4 * g + r));
#pragma unroll
      for (int n = 0; n < 4; n++)
#pragma unroll
        for (int r = 0; r < 4; r++) o[n][r] *= scr[r];
#pragma unroll
      for (int r = 0; r < 4; r++) osum[r] *= scr[r];
    }

    // P pack: [16q][32kv] bf16, 80B rows (conflict-free)
#pragma unroll
    for (int t = 0; t < 2; t++) {
      bf16x4 pv = {(bf16)__builtin_amdgcn_exp2f(s[t][0] - m2),
                   (bf16)__builtin_amdgcn_exp2f(s[t][1] - m2),
                   (bf16)__builtin_amdgcn_exp2f(s[t][2] - m2),
                   (bf16)__builtin_amdgcn_exp2f(s[t][3] - m2)};
      const int L = 2 * t + (g >> 1);
      *(bf16x4*)(pwv + c * 80 + L * 16 + (g & 1) * 8) = pv;
    }
    bf16x8 pa = *(const bf16x8*)(pwv + c * 80 + g * 16);

    // PV + row-sum via ones-MFMA
    __builtin_amdgcn_s_setprio(1);
#pragma unroll
    for (int n = 0; n < 4; n++) {
      bf16x8 vf = *(const bf16x8*)(v0 + (n * 16 + c) * 80 + g * 16);
      o[n] = __builtin_amdgcn_mfma_f32_16x16x32_bf16(pa, vf, o[n], 0, 0, 0);
    }
    osum = __builtin_amdgcn_mfma_f32_16x16x32_bf16(pa, ones, osum, 0, 0, 0);
    __builtin_amdgcn_s_setprio(0);

    // rotate ring: current <- next, next <- staged, staged <- old current
    char* tk = k0; k0 = k1; k1 = k2; k2 = tk;
    char* tv = v0; v0 = v1; v1 = v2; v2 = tv;
    char* tc = c0; c0 = c1; c1 = c2; c2 = tc;
  }

  // epilogue: write partials {m2, osum, o[64] bf16} per q-row (144B rows)
  float m2r[4];
#pragma unroll
  for (int r = 0; r < 4; r++)
    m2r[r] = __shfl(m2, (lane & 48) | (4 * g + r));
  char* pb0 = part + ks * PS + ((int64_t)bh * 4096 + qw) * 144;
#pragma unroll
  for (int r = 0; r < 4; r++) {
    char* pb = pb0 + (g * 4 + r) * 144;
    if (c == 0) {
      *(float*)pb = m2r[r];
      *((float*)pb + 1) = osum[r];
    }
#pragma unroll
    for (int n = 0; n < 4; n++)
      *(bf16*)(pb + 16 + (n * 16 + c) * 2) = (bf16)o[n][r];
  }
}

// ---------------- combine: merge the 2 kv-split partials -> Ob -------------
__global__ __launch_bounds__(256) void combine_kernel(
    const char* __restrict__ part, bf16* __restrict__ Ob) {
  const int t = blockIdx.x * 256 + threadIdx.x;
  const int row = t >> 6;  // bh*4096 + q, 0..65535
  const int e = t & 63;
  const char* p0 = part + (int64_t)row * 144;
  const char* p1 = p0 + PS;
  const float m0 = *(const float*)p0, s0 = *((const float*)p0 + 1);
  const float m1 = *(const float*)p1, s1 = *((const float*)p1 + 1);
  const float o0 = (float)*(const bf16*)(p0 + 16 + e * 2);
  const float o1 = (float)*(const bf16*)(p1 + 16 + e * 2);
  const float m = fmaxf(m0, m1);
  const float w0 = __builtin_amdgcn_exp2f(m0 - m);
  const float w1 = __builtin_amdgcn_exp2f(m1 - m);
  const float res = (o0 * w0 + o1 * w1) / (s0 * w0 + s1 * w1);
  const int bh = row >> 12, q = row & 4095;
  Ob[((int64_t)((bh >> 3) * 4096 + q)) * 512 + (bh & 7) * 64 + e] = (bf16)res;
}

// ---------------- launch ---------------------------------------------------
extern "C" void kernel_launch(void* const* d_in, const int* in_sizes, int n_in,
                              void* d_out, int out_size, void* d_ws,
                              size_t ws_size, hipStream_t stream) {
  const float* x = (const float*)d_in[0];
  const float* coords = (const float*)d_in[1];
  const float* Wq = (const float*)d_in[2];
  const float* bq = (const float*)d_in[3];
  const float* Wk = (const float*)d_in[4];
  const float* bk = (const float*)d_in[5];
  const float* Wv = (const float*)d_in[6];
  const float* bv = (const float*)d_in[7];
  const float* Wp = (const float*)d_in[8];
  const float* bp = (const float*)d_in[9];
  const float* slopes = (const float*)d_in[10];

  char* ws = (char*)d_ws;
  bf16* xb = (bf16*)(ws);
  bf16* Wt = (bf16*)(ws + 8388608);
  bf16* Wpt = (bf16*)(ws + 9961472);
  bf16* Qb = (bf16*)(ws + 10485760);
  bf16* Kb = (bf16*)(ws + 18874368);
  bf16* Vt = (bf16*)(ws + 27262976);
  bf16* Ob = (bf16*)(ws + 35651584);
  char* part = ws + 44040192;  // 2 * PS = 18,874,368 B -> ends at ~62.9 MB

  hipLaunchKernelGGL(prep_kernel, dim3(1024), dim3(256), 0, stream, x, Wq, Wk,
                     Wv, Wp, xb, Wt, Wpt);
  hipLaunchKernelGGL(qkv_gemm, dim3(12, 64), dim3(256), 0, stream, xb, Wt, bq,
                     bk, bv, Qb, Kb, Vt);
  hipLaunchKernelGGL(attn_kernel, dim3(1024), dim3(512), 0, stream, Qb, Kb,
                     Vt, coords, slopes, part);
  hipLaunchKernelGGL(combine_kernel, dim3(16384), dim3(256), 0, stream, part,
                     Ob);
  hipLaunchKernelGGL(out_gemm, dim3(4, 64), dim3(256), 0, stream, Ob, Wpt, bp,
                     (float*)d_out);
}

// Round 12
// 215.054 us; speedup vs baseline: 1.2645x; 1.2645x over previous
//
#include <hip/hip_runtime.h>
#include <stdint.h>

typedef __bf16 bf16;
typedef __attribute__((ext_vector_type(8))) __bf16 bf16x8;
typedef __attribute__((ext_vector_type(4))) __bf16 bf16x4;
typedef __attribute__((ext_vector_type(4))) float f32x4;

#define DEVFN static __device__ __forceinline__

DEVFN void gload16(const bf16* g, char* l) {
  __builtin_amdgcn_global_load_lds(
      (const __attribute__((address_space(1))) void*)g,
      (__attribute__((address_space(3))) void*)l, 16, 0, 0);
}
DEVFN void gload4(const float* g, char* l) {
  __builtin_amdgcn_global_load_lds(
      (const __attribute__((address_space(1))) void*)g,
      (__attribute__((address_space(3))) void*)l, 4, 0, 0);
}

DEVFN int swz(int row, int kb) { return row * 128 + (kb ^ ((row & 7) << 4)); }

#define PS 9437184LL  // partial stride per kv-split: 16 bh * 4096 q * 144 B

// ---------------- prep: fp32 -> bf16 + weight transposes --------------------
__global__ __launch_bounds__(256) void prep_kernel(
    const float* __restrict__ x, const float* __restrict__ Wq,
    const float* __restrict__ Wk, const float* __restrict__ Wv,
    const float* __restrict__ Wp, bf16* __restrict__ xb,
    bf16* __restrict__ Wt, bf16* __restrict__ Wpt) {
  const int64_t tid = blockIdx.x * 256LL + threadIdx.x;
  const int64_t stride = (int64_t)gridDim.x * 256LL;
  for (int64_t i = tid; i < (8192LL * 512) / 4; i += stride) {
    float4 v = ((const float4*)x)[i];
    bf16x4 o = {(bf16)v.x, (bf16)v.y, (bf16)v.z, (bf16)v.w};
    ((bf16x4*)xb)[i] = o;
  }
  for (int64_t i = tid; i < 1536LL * 512; i += stride) {
    int c = (int)(i >> 9), k = (int)(i & 511);
    int wsel = c >> 9, cc = c & 511;
    const float* W = wsel == 0 ? Wq : (wsel == 1 ? Wk : Wv);
    Wt[i] = (bf16)W[k * 512 + cc];
  }
  for (int64_t i = tid; i < 512LL * 512; i += stride) {
    int c = (int)(i >> 9), k = (int)(i & 511);
    Wpt[i] = (bf16)Wp[k * 512 + c];
  }
}

// ---------------- shared 128x128 bf16 GEMM mainloop (K=512, BK=64) ----------
DEVFN void gemm_main(const bf16* __restrict__ A, const bf16* __restrict__ B,
                     int rowA0, int rowB0, char* sA, char* sB, f32x4 acc[4][4],
                     int wr, int wc, int lane, int w) {
#pragma unroll
  for (int m = 0; m < 4; m++)
#pragma unroll
    for (int n = 0; n < 4; n++) acc[m][n] = (f32x4){0.f, 0.f, 0.f, 0.f};
  const int lr = lane >> 3;
  const int kswz = 8 * ((lane & 7) ^ lr);
  for (int k0 = 0; k0 < 512; k0 += 64) {
#pragma unroll
    for (int j = 0; j < 4; j++) {
      const int c = w * 4 + j;
      gload16(A + (rowA0 + c * 8 + lr) * 512 + k0 + kswz, sA + c * 1024);
      gload16(B + (rowB0 + c * 8 + lr) * 512 + k0 + kswz, sB + c * 1024);
    }
    __syncthreads();
    bf16x8 af[4][2], bfv[4][2];
#pragma unroll
    for (int m = 0; m < 4; m++)
#pragma unroll
      for (int kk = 0; kk < 2; kk++) {
        af[m][kk] = *(const bf16x8*)(sA + swz(wr * 64 + m * 16 + (lane & 15),
                                              kk * 64 + (lane >> 4) * 16));
        bfv[m][kk] = *(const bf16x8*)(sB + swz(wc * 64 + m * 16 + (lane & 15),
                                               kk * 64 + (lane >> 4) * 16));
      }
#pragma unroll
    for (int m = 0; m < 4; m++)
#pragma unroll
      for (int n = 0; n < 4; n++)
#pragma unroll
        for (int kk = 0; kk < 2; kk++)
          acc[m][n] = __builtin_amdgcn_mfma_f32_16x16x32_bf16(
              af[m][kk], bfv[n][kk], acc[m][n], 0, 0, 0);
    __syncthreads();
  }
}

// ---------------- QKV projection ------------------------------------------
// Q is pre-scaled by 0.125*log2(e) so attention folds the softmax scale.
__global__ __launch_bounds__(256) void qkv_gemm(
    const bf16* __restrict__ xb, const bf16* __restrict__ Wt,
    const float* __restrict__ bq, const float* __restrict__ bk,
    const float* __restrict__ bv, bf16* __restrict__ Qb, bf16* __restrict__ Kb,
    bf16* __restrict__ Vt) {
  __shared__ __align__(128) char sA[16384];
  __shared__ __align__(128) char sB[16384];
  const int lane = threadIdx.x & 63, w = threadIdx.x >> 6;
  const int wr = w >> 1, wc = w & 1;
  const int rowA0 = blockIdx.y * 128;
  const int colB0 = blockIdx.x * 128;
  f32x4 acc[4][4];
  gemm_main(xb, Wt, rowA0, colB0, sA, sB, acc, wr, wc, lane, w);
  const int which = colB0 >> 9;
  const int cc0 = colB0 & 511;
  const float* bias = which == 0 ? bq : (which == 1 ? bk : bv);
  const float QSCALE = 0.18033688011112042f;  // 0.125 * log2(e)
#pragma unroll
  for (int m = 0; m < 4; m++)
#pragma unroll
    for (int n = 0; n < 4; n++)
#pragma unroll
      for (int r = 0; r < 4; r++) {
        int row = rowA0 + wr * 64 + m * 16 + (lane >> 4) * 4 + r;
        int col = cc0 + wc * 64 + n * 16 + (lane & 15);
        float v = acc[m][n][r] + bias[col];
        if (which == 0) {
          Qb[(int64_t)row * 512 + col] = (bf16)(v * QSCALE);
        } else if (which == 1) {
          Kb[(int64_t)row * 512 + col] = (bf16)v;
        } else {
          int b = row >> 12, nn = row & 4095;
          int hh = col >> 6, e = col & 63;
          Vt[(((int64_t)(b * 8 + hh)) * 64 + e) * 4096 + nn] = (bf16)v;
        }
      }
}

// ---------------- output projection (fp32 out) ----------------------------
__global__ __launch_bounds__(256) void out_gemm(const bf16* __restrict__ Ob,
                                                const bf16* __restrict__ Wpt,
                                                const float* __restrict__ bp,
                                                float* __restrict__ out) {
  __shared__ __align__(128) char sA[16384];
  __shared__ __align__(128) char sB[16384];
  const int lane = threadIdx.x & 63, w = threadIdx.x >> 6;
  const int wr = w >> 1, wc = w & 1;
  const int rowA0 = blockIdx.y * 128;
  const int colB0 = blockIdx.x * 128;
  f32x4 acc[4][4];
  gemm_main(Ob, Wpt, rowA0, colB0, sA, sB, acc, wr, wc, lane, w);
#pragma unroll
  for (int m = 0; m < 4; m++)
#pragma unroll
    for (int n = 0; n < 4; n++)
#pragma unroll
      for (int r = 0; r < 4; r++) {
        int row = rowA0 + wr * 64 + m * 16 + (lane >> 4) * 4 + r;
        int col = colB0 + wc * 64 + n * 16 + (lane & 15);
        out[(int64_t)row * 512 + col] = acc[m][n][r] + bp[col];
      }
}

// ---------------- fused flash attention: async-LDS, KVBLK=64, kv-split -----
// Block = 1 head, 8 waves = 8 q-subwaves (16 q each, q-tile 128), half the
// kv range (2048 = 32 tiles of KVBLK=64). Grid 1024. Round-9 sync structure
// (STAGE(t+1) at top, __syncthreads at bottom) with half the iterations:
// per-iter fixed costs (barrier drain, max-reduce, branch) amortize 2x.
// K/V: [64][128B] XOR-swizzled rows, staged via 1 gload16/wave each with
// pre-swizzled global source. Deferred-max: per-lane check, shfl only in
// the rare rescale branch. Partials (m2, osum, o bf16) -> combine kernel.
__global__ __launch_bounds__(512) void attn_kernel(
    const bf16* __restrict__ Qb, const bf16* __restrict__ Kb,
    const bf16* __restrict__ Vt, const float* __restrict__ coords,
    const float* __restrict__ slopes, char* __restrict__ part) {
  __shared__ __align__(128) char sK[2 * 8192];  // [buf][64 kv][128B] swz
  __shared__ __align__(128) char sV[2 * 8192];  // [buf][64 e][128B] swz
  __shared__ __align__(128) char sC[2 * 512];   // [buf][64 kv float2]
  __shared__ __align__(128) char sP[8 * 2048];  // per-wave P [16q][128B] swz

  const int tid = threadIdx.x;
  const int lane = tid & 63, w = tid >> 6;
  const int c = lane & 15, g = lane >> 4;

  const int id = blockIdx.x;          // 0..1023
  const int bh = id & 15;             // bh%8 -> XCD
  const int qt = (id >> 4) & 31;
  const int ks = id >> 9;             // kv half
  const int b = bh >> 3, h = bh & 7;
  const int qw = qt * 128 + w * 16;
  const int bO = b * 4096;
  const int kvs = ks * 2048;

  const float LOG2E = 1.4426950408889634f;
  const float negsl2 = -slopes[h] * LOG2E;

  // Q fragments (B-operand of swapped QK^T): lane holds Q[q=c][hd=g*8+j]
  bf16x8 aq[2];
  {
    int64_t base = ((int64_t)(bO + qw + c)) * 512 + h * 64 + g * 8;
    aq[0] = *(const bf16x8*)(Qb + base);
    aq[1] = *(const bf16x8*)(Qb + base + 32);
  }
  const float* cbf = coords + (int64_t)bO * 2;
  float qcx, qcy;
  {
    float2 qc = ((const float2*)cbf)[qw + c];
    qcx = qc.x;
    qcy = qc.y;
  }

  bf16x8 ones;
#pragma unroll
  for (int jj = 0; jj < 8; jj++) ones[jj] = (bf16)1.0f;

  float m2 = -1e30f;
  f32x4 o[4], osum;
#pragma unroll
  for (int n = 0; n < 4; n++) o[n] = (f32x4){0.f, 0.f, 0.f, 0.f};
  osum = (f32x4){0.f, 0.f, 0.f, 0.f};

  const bf16* Kp = Kb + (int64_t)bO * 512 + h * 64;
  const bf16* Vp = Vt + (int64_t)(b * 8 + h) * 262144;

  // -------- staging: 1 K-granule + 1 V-granule per wave (+coords on w2/w3)
  // granule gi = row*8 + j; LDS dest linear gi*16; source column pre-swizzled
  // j -> j ^ (row&7) so the LDS read swizzle sees conflict-free rows.
  const int gi = w * 64 + lane;
  const int kr = gi >> 3, kj = gi & 7;
  const bf16* kq =
      Kp + (int64_t)(kvs + kr) * 512 + ((kj ^ (kr & 7)) * 8);
  const bf16* vq = Vp + kr * 4096 + kvs + ((kj ^ (kr & 7)) * 8);
  const float* cq = cbf + kvs * 2 + (w & 1) * 64 + lane;  // w2,w3 only

  auto STAGE = [&](int bb) {
    gload16(kq, sK + bb * 8192 + gi * 16);
    kq += 64 * 512;
    gload16(vq, sV + bb * 8192 + gi * 16);
    vq += 64;
    if (w == 2 || w == 3) {
      gload4(cq, sC + bb * 512 + (w & 1) * 256);
      cq += 128;
    }
  };

  STAGE(0);
  __syncthreads();

  char* pwv = sP + w * 2048;
  const int cm = c & 7;
  for (int tt = 0; tt < 32; ++tt) {
    const int bb = tt & 1;
    if (tt + 1 < 32) STAGE(bb ^ 1);

    const char* kb = sK + bb * 8192;
    const char* vb = sV + bb * 8192;
    const char* cb0 = sC + bb * 512;

    // S^T = (K Q^T): lane holds q=c, kv = 16t+4g+r, t in 0..3
    bf16x8 kf[4][2];
#pragma unroll
    for (int t = 0; t < 4; t++)
#pragma unroll
      for (int kk = 0; kk < 2; kk++)
        kf[t][kk] = *(const bf16x8*)(kb + (t * 16 + c) * 128 +
                                     (((kk * 4 + g) ^ cm) * 16));
    float s[4][4];
    __builtin_amdgcn_s_setprio(1);
#pragma unroll
    for (int t = 0; t < 4; t++) {
      f32x4 sa = (f32x4){0.f, 0.f, 0.f, 0.f};
      sa = __builtin_amdgcn_mfma_f32_16x16x32_bf16(kf[t][0], aq[0], sa, 0, 0, 0);
      sa = __builtin_amdgcn_mfma_f32_16x16x32_bf16(kf[t][1], aq[1], sa, 0, 0, 0);
#pragma unroll
      for (int r = 0; r < 4; r++) s[t][r] = sa[r];
    }
    __builtin_amdgcn_s_setprio(0);

    // in-register bias from LDS-staged coords (broadcast reads)
#pragma unroll
    for (int t = 0; t < 4; t++) {
      f32x4 ca = *(const f32x4*)(cb0 + 128 * t + 32 * g);
      f32x4 cb2 = *(const f32x4*)(cb0 + 128 * t + 32 * g + 16);
      float dx, dy;
#define DIST1(T, R, CX, CY)                                              \
  dx = qcx - (CX);                                                       \
  dy = qcy - (CY);                                                       \
  s[T][R] = __builtin_fmaf(__builtin_amdgcn_sqrtf(dx * dx + dy * dy),    \
                           negsl2, s[T][R]);
      DIST1(t, 0, ca[0], ca[1])
      DIST1(t, 1, ca[2], ca[3])
      DIST1(t, 2, cb2[0], cb2[1])
      DIST1(t, 3, cb2[2], cb2[3])
#undef DIST1
    }

    // deferred online max (THR=8 base-2): per-lane check, reduce in branch
    float lm = fmaxf(fmaxf(fmaxf(s[0][0], s[0][1]), fmaxf(s[0][2], s[0][3])),
                     fmaxf(fmaxf(s[1][0], s[1][1]), fmaxf(s[1][2], s[1][3])));
    lm = fmaxf(lm,
               fmaxf(fmaxf(fmaxf(s[2][0], s[2][1]), fmaxf(s[2][2], s[2][3])),
                     fmaxf(fmaxf(s[3][0], s[3][1]), fmaxf(s[3][2], s[3][3]))));
    if (__any(lm > m2 + 8.f)) {
      float lmf = fmaxf(lm, __shfl_xor(lm, 16));
      lmf = fmaxf(lmf, __shfl_xor(lmf, 32));
      float nm = fmaxf(m2, lmf);
      float sc = __builtin_amdgcn_exp2f(m2 - nm);
      m2 = nm;
      float scr[4];
#pragma unroll
      for (int r = 0; r < 4; r++)
        scr[r] = __shfl(sc, (lane & 48) | (4 * g + r));
#pragma unroll
      for (int n = 0; n < 4; n++)
#pragma unroll
        for (int r = 0; r < 4; r++) o[n][r] *= scr[r];
#pragma unroll
      for (int r = 0; r < 4; r++) osum[r] *= scr[r];
    }

    // P pack: [16q][64kv] bf16, 128B XOR-swizzled rows
#pragma unroll
    for (int t = 0; t < 4; t++) {
      bf16x4 pv = {(bf16)__builtin_amdgcn_exp2f(s[t][0] - m2),
                   (bf16)__builtin_amdgcn_exp2f(s[t][1] - m2),
                   (bf16)__builtin_amdgcn_exp2f(s[t][2] - m2),
                   (bf16)__builtin_amdgcn_exp2f(s[t][3] - m2)};
      *(bf16x4*)(pwv + c * 128 + (((2 * t + (g >> 1)) ^ cm) * 16) +
                 (g & 1) * 8) = pv;
    }
    bf16x8 pa0 = *(const bf16x8*)(pwv + c * 128 + ((g ^ cm) * 16));
    bf16x8 pa1 = *(const bf16x8*)(pwv + c * 128 + (((4 + g) ^ cm) * 16));

    // PV + row-sum via ones-MFMA
    __builtin_amdgcn_s_setprio(1);
#pragma unroll
    for (int n = 0; n < 4; n++) {
      const int e = n * 16 + c;
      bf16x8 vf0 = *(const bf16x8*)(vb + e * 128 + ((g ^ (e & 7)) * 16));
      bf16x8 vf1 = *(const bf16x8*)(vb + e * 128 + (((4 + g) ^ (e & 7)) * 16));
      o[n] = __builtin_amdgcn_mfma_f32_16x16x32_bf16(pa0, vf0, o[n], 0, 0, 0);
      o[n] = __builtin_amdgcn_mfma_f32_16x16x32_bf16(pa1, vf1, o[n], 0, 0, 0);
    }
    osum = __builtin_amdgcn_mfma_f32_16x16x32_bf16(pa0, ones, osum, 0, 0, 0);
    osum = __builtin_amdgcn_mfma_f32_16x16x32_bf16(pa1, ones, osum, 0, 0, 0);
    __builtin_amdgcn_s_setprio(0);

    __syncthreads();
  }

  // epilogue: write partials {m2, osum, o[64] bf16} per q-row (144B rows)
  float m2r[4];
#pragma unroll
  for (int r = 0; r < 4; r++)
    m2r[r] = __shfl(m2, (lane & 48) | (4 * g + r));
  char* pb0 = part + ks * PS + ((int64_t)bh * 4096 + qw) * 144;
#pragma unroll
  for (int r = 0; r < 4; r++) {
    char* pb = pb0 + (g * 4 + r) * 144;
    if (c == 0) {
      *(float*)pb = m2r[r];
      *((float*)pb + 1) = osum[r];
    }
#pragma unroll
    for (int n = 0; n < 4; n++)
      *(bf16*)(pb + 16 + (n * 16 + c) * 2) = (bf16)o[n][r];
  }
}

// ---------------- combine: merge the 2 kv-split partials -> Ob -------------
__global__ __launch_bounds__(256) void combine_kernel(
    const char* __restrict__ part, bf16* __restrict__ Ob) {
  const int t = blockIdx.x * 256 + threadIdx.x;
  const int row = t >> 6;  // bh*4096 + q, 0..65535
  const int e = t & 63;
  const char* p0 = part + (int64_t)row * 144;
  const char* p1 = p0 + PS;
  const float m0 = *(const float*)p0, s0 = *((const float*)p0 + 1);
  const float m1 = *(const float*)p1, s1 = *((const float*)p1 + 1);
  const float o0 = (float)*(const bf16*)(p0 + 16 + e * 2);
  const float o1 = (float)*(const bf16*)(p1 + 16 + e * 2);
  const float m = fmaxf(m0, m1);
  const float w0 = __builtin_amdgcn_exp2f(m0 - m);
  const float w1 = __builtin_amdgcn_exp2f(m1 - m);
  const float res = (o0 * w0 + o1 * w1) / (s0 * w0 + s1 * w1);
  const int bh = row >> 12, q = row & 4095;
  Ob[((int64_t)((bh >> 3) * 4096 + q)) * 512 + (bh & 7) * 64 + e] = (bf16)res;
}

// ---------------- launch ---------------------------------------------------
extern "C" void kernel_launch(void* const* d_in, const int* in_sizes, int n_in,
                              void* d_out, int out_size, void* d_ws,
                              size_t ws_size, hipStream_t stream) {
  const float* x = (const float*)d_in[0];
  const float* coords = (const float*)d_in[1];
  const float* Wq = (const float*)d_in[2];
  const float* bq = (const float*)d_in[3];
  const float* Wk = (const float*)d_in[4];
  const float* bk = (const float*)d_in[5];
  const float* Wv = (const float*)d_in[6];
  const float* bv = (const float*)d_in[7];
  const float* Wp = (const float*)d_in[8];
  const float* bp = (const float*)d_in[9];
  const float* slopes = (const float*)d_in[10];

  char* ws = (char*)d_ws;
  bf16* xb = (bf16*)(ws);
  bf16* Wt = (bf16*)(ws + 8388608);
  bf16* Wpt = (bf16*)(ws + 9961472);
  bf16* Qb = (bf16*)(ws + 10485760);
  bf16* Kb = (bf16*)(ws + 18874368);
  bf16* Vt = (bf16*)(ws + 27262976);
  bf16* Ob = (bf16*)(ws + 35651584);
  char* part = ws + 44040192;  // 2 * PS = 18,874,368 B -> ends at ~62.9 MB

  hipLaunchKernelGGL(prep_kernel, dim3(1024), dim3(256), 0, stream, x, Wq, Wk,
                     Wv, Wp, xb, Wt, Wpt);
  hipLaunchKernelGGL(qkv_gemm, dim3(12, 64), dim3(256), 0, stream, xb, Wt, bq,
                     bk, bv, Qb, Kb, Vt);
  hipLaunchKernelGGL(attn_kernel, dim3(1024), dim3(512), 0, stream, Qb, Kb,
                     Vt, coords, slopes, part);
  hipLaunchKernelGGL(combine_kernel, dim3(16384), dim3(256), 0, stream, part,
                     Ob);
  hipLaunchKernelGGL(out_gemm, dim3(4, 64), dim3(256), 0, stream, Ob, Wpt, bp,
                     (float*)d_out);
}